// Round 2
// baseline (107.147 us; speedup 1.0000x reference)
//
#include <hip/hip_runtime.h>

#define TPX 4                  // pixels per thread (x)
#define BX 16
#define BY 16
#define TILE_W (BX*TPX)        // 64
#define TILE_H BY              // 16
#define HALO 3
#define SW_V (TILE_W + 2*HALO) // 70 valid cols
#define SROW 72                // padded row stride (multiple of 4 floats -> b128 aligned)
#define SH_T (TILE_H + 2*HALO) // 22
#define H_IMG 512
#define W_IMG 512

__device__ __forceinline__ int reflect_idx(int q, int n) {
    q = (q < 0) ? -q : q;
    q = (q >= n) ? (2 * n - 2 - q) : q;
    return q;
}

__global__ __launch_bounds__(256) void AdaptiveFilter_71416716198124_kernel(
    const float* __restrict__ x,
    const float* __restrict__ g,
    const float* __restrict__ w0,
    float* __restrict__ out)
{
    __shared__ __align__(16) float sg[3][SH_T][SROW];
    __shared__ __align__(16) float sx[3][SH_T][SROW];

    const int b   = blockIdx.z;
    const int h0  = blockIdx.y * TILE_H;
    const int w0c = blockIdx.x * TILE_W;
    const int tid = threadIdx.y * BX + threadIdx.x;
    const int plane = H_IMG * W_IMG;
    const float* gb = g + (size_t)b * 3 * plane;
    const float* xb = x + (size_t)b * 3 * plane;

    // Stage tile + halo (reflect at borders). Coalesced along rows.
    for (int idx = tid; idx < 3 * SH_T * SW_V; idx += BX * BY) {
        int c  = idx / (SH_T * SW_V);
        int r  = idx - c * (SH_T * SW_V);
        int sh = r / SW_V;
        int sw = r - sh * SW_V;
        int gh = reflect_idx(h0 + sh - HALO, H_IMG);
        int gw = reflect_idx(w0c + sw - HALO, W_IMG);
        int off = c * plane + gh * W_IMG + gw;
        sg[c][sh][sw] = gb[off];
        sx[c][sh][sw] = xb[off];
    }
    __syncthreads();

    const int lx4 = threadIdx.x * TPX;
    const int ly  = threadIdx.y;
    const int h   = h0 + ly;
    const int wb  = w0c + lx4;

    // Per-pixel 16 stored half-kernel logits; softmax denom cancels in num/den,
    // so only exp(l - max) is needed. Max over the 16 stored values (the full
    // 7x7 kernel only contains those via reflect map m(i)=i<4?i:6-i).
    float lw[TPX][16];
    #pragma unroll
    for (int p = 0; p < TPX; p++) {
        const float4* wp = (const float4*)(w0 +
            (((size_t)b * plane + (size_t)h * W_IMG + (wb + p)) << 4));
        float4 a0 = wp[0], a1 = wp[1], a2 = wp[2], a3 = wp[3];
        float v[16] = {a0.x,a0.y,a0.z,a0.w, a1.x,a1.y,a1.z,a1.w,
                       a2.x,a2.y,a2.z,a2.w, a3.x,a3.y,a3.z,a3.w};
        float mx = v[0];
        #pragma unroll
        for (int k = 1; k < 16; k++) mx = fmaxf(mx, v[k]);
        #pragma unroll
        for (int k = 0; k < 16; k++) lw[p][k] = v[k] - mx;
    }

    float gc[TPX][3];
    #pragma unroll
    for (int p = 0; p < TPX; p++)
        #pragma unroll
        for (int c = 0; c < 3; c++)
            gc[p][c] = sg[c][ly + HALO][lx4 + HALO + p];

    float acc[TPX][3] = {};
    float den[TPX] = {};

    #pragma unroll
    for (int i = 0; i < 7; i++) {
        const int mi4 = ((i < 4) ? i : 6 - i) * 4;

        // 1) accumulate per-tap color distance over channels (3 ds_read_b128 each)
        float sd[TPX][7];
        #pragma unroll
        for (int p = 0; p < TPX; p++)
            #pragma unroll
            for (int j = 0; j < 7; j++) sd[p][j] = 0.f;

        #pragma unroll
        for (int c = 0; c < 3; c++) {
            const float4* pg = (const float4*)&sg[c][ly + i][lx4];
            float4 g0 = pg[0], g1 = pg[1], g2 = pg[2];
            float rg[12] = {g0.x,g0.y,g0.z,g0.w, g1.x,g1.y,g1.z,g1.w,
                            g2.x,g2.y,g2.z,g2.w};
            #pragma unroll
            for (int p = 0; p < TPX; p++) {
                const float cc = gc[p][c];
                #pragma unroll
                for (int j = 0; j < 7; j++)
                    sd[p][j] += fabsf(rg[p + j] - cc);
            }
        }

        // 2) turn distances into weights: wt = exp(lw - 50*s^2)
        #pragma unroll
        for (int p = 0; p < TPX; p++) {
            #pragma unroll
            for (int j = 0; j < 7; j++) {
                const int mj = (j < 4) ? j : 6 - j;
                const float s = sd[p][j];
                sd[p][j] = __expf(fmaf(-50.0f * s, s, lw[p][mi4 + mj]));
            }
        }

        // 3) accumulate weighted x and denominator
        #pragma unroll
        for (int c = 0; c < 3; c++) {
            const float4* px = (const float4*)&sx[c][ly + i][lx4];
            float4 x0 = px[0], x1 = px[1], x2 = px[2];
            float rx[12] = {x0.x,x0.y,x0.z,x0.w, x1.x,x1.y,x1.z,x1.w,
                            x2.x,x2.y,x2.z,x2.w};
            #pragma unroll
            for (int p = 0; p < TPX; p++) {
                float a = acc[p][c];
                #pragma unroll
                for (int j = 0; j < 7; j++)
                    a = fmaf(rx[p + j], sd[p][j], a);
                acc[p][c] = a;
            }
        }
        #pragma unroll
        for (int p = 0; p < TPX; p++) {
            #pragma unroll
            for (int j = 0; j < 7; j++) den[p] += sd[p][j];
        }
    }

    float inv[TPX];
    #pragma unroll
    for (int p = 0; p < TPX; p++) inv[p] = 1.0f / den[p];

    #pragma unroll
    for (int c = 0; c < 3; c++) {
        float4 o;
        o.x = acc[0][c] * inv[0];
        o.y = acc[1][c] * inv[1];
        o.z = acc[2][c] * inv[2];
        o.w = acc[3][c] * inv[3];
        *(float4*)(out + (size_t)(b * 3 + c) * plane + (size_t)h * W_IMG + wb) = o;
    }
}

extern "C" void kernel_launch(void* const* d_in, const int* in_sizes, int n_in,
                              void* d_out, int out_size, void* d_ws, size_t ws_size,
                              hipStream_t stream) {
    const float* x  = (const float*)d_in[0];
    const float* g  = (const float*)d_in[1];
    const float* w0 = (const float*)d_in[2];
    float* out = (float*)d_out;

    dim3 block(BX, BY, 1);
    dim3 grid(W_IMG / TILE_W, H_IMG / TILE_H, 2);
    AdaptiveFilter_71416716198124_kernel<<<grid, block, 0, stream>>>(x, g, w0, out);
}

// Round 3
// 102.431 us; speedup vs baseline: 1.0460x; 1.0460x over previous
//
#include <hip/hip_runtime.h>

#define TPX 2                  // pixels per thread (x)
#define BX 32
#define BY 8
#define TILE_W (BX*TPX)        // 64
#define TILE_H BY              // 8
#define HALO 3
#define SW_V (TILE_W + 2*HALO) // 70 valid cols
#define SROW 72                // padded row stride (float2/float4-aligned)
#define SH_T (TILE_H + 2*HALO) // 14
#define H_IMG 512
#define W_IMG 512

__device__ __forceinline__ int reflect_idx(int q, int n) {
    q = (q < 0) ? -q : q;
    q = (q >= n) ? (2 * n - 2 - q) : q;
    return q;
}

__global__ __launch_bounds__(256) void AdaptiveFilter_71416716198124_kernel(
    const float* __restrict__ x,
    const float* __restrict__ g,
    const float* __restrict__ w0,
    float* __restrict__ out)
{
    __shared__ __align__(16) float sg[3][SH_T][SROW];
    __shared__ __align__(16) float sx[3][SH_T][SROW];

    const int b   = blockIdx.z;
    const int h0  = blockIdx.y * TILE_H;
    const int w0c = blockIdx.x * TILE_W;
    const int tid = threadIdx.y * BX + threadIdx.x;
    const int plane = H_IMG * W_IMG;
    const float* gb = g + (size_t)b * 3 * plane;
    const float* xb = x + (size_t)b * 3 * plane;

    // Stage tile + halo (reflect at borders). Coalesced along rows.
    for (int idx = tid; idx < 3 * SH_T * SW_V; idx += BX * BY) {
        int c  = idx / (SH_T * SW_V);
        int r  = idx - c * (SH_T * SW_V);
        int sh = r / SW_V;
        int sw = r - sh * SW_V;
        int gh = reflect_idx(h0 + sh - HALO, H_IMG);
        int gw = reflect_idx(w0c + sw - HALO, W_IMG);
        int off = c * plane + gh * W_IMG + gw;
        sg[c][sh][sw] = gb[off];
        sx[c][sh][sw] = xb[off];
    }
    __syncthreads();

    const int lx2 = threadIdx.x * TPX;
    const int ly  = threadIdx.y;
    const int h   = h0 + ly;
    const int wb  = w0c + lx2;

    // Per-pixel 16 stored half-kernel logits. Softmax denominator cancels in
    // num/den, so we only need exp(l - max); max over the 16 stored logits
    // (the reflected 7x7 kernel contains only these via m(i)=i<4?i:6-i).
    float lw[TPX][16];
    #pragma unroll
    for (int p = 0; p < TPX; p++) {
        const float4* wp = (const float4*)(w0 +
            (((size_t)b * plane + (size_t)h * W_IMG + (wb + p)) << 4));
        float4 a0 = wp[0], a1 = wp[1], a2 = wp[2], a3 = wp[3];
        float v[16] = {a0.x,a0.y,a0.z,a0.w, a1.x,a1.y,a1.z,a1.w,
                       a2.x,a2.y,a2.z,a2.w, a3.x,a3.y,a3.z,a3.w};
        float mx = v[0];
        #pragma unroll
        for (int k = 1; k < 16; k++) mx = fmaxf(mx, v[k]);
        #pragma unroll
        for (int k = 0; k < 16; k++) lw[p][k] = v[k] - mx;
    }

    float gc[TPX][3];
    #pragma unroll
    for (int p = 0; p < TPX; p++)
        #pragma unroll
        for (int c = 0; c < 3; c++)
            gc[p][c] = sg[c][ly + HALO][lx2 + HALO + p];

    float acc[TPX][3] = {};
    float den[TPX] = {};

    #pragma unroll
    for (int i = 0; i < 7; i++) {
        const int mi4 = ((i < 4) ? i : 6 - i) * 4;

        // 1) per-tap color distance summed over channels.
        //    Window for 2 pixels x 7 taps = floats [0..7] -> 4x ds_read_b64.
        float sd[TPX][7] = {};
        #pragma unroll
        for (int c = 0; c < 3; c++) {
            const float2* pg = (const float2*)&sg[c][ly + i][lx2];
            float2 g0 = pg[0], g1 = pg[1], g2 = pg[2], g3 = pg[3];
            float rg[8] = {g0.x,g0.y, g1.x,g1.y, g2.x,g2.y, g3.x,g3.y};
            #pragma unroll
            for (int p = 0; p < TPX; p++) {
                const float cc = gc[p][c];
                #pragma unroll
                for (int j = 0; j < 7; j++)
                    sd[p][j] += fabsf(rg[p + j] - cc);
            }
        }

        // 2) weights: wt = exp(lw - 50*s^2)
        #pragma unroll
        for (int p = 0; p < TPX; p++) {
            #pragma unroll
            for (int j = 0; j < 7; j++) {
                const int mj = (j < 4) ? j : 6 - j;
                const float s = sd[p][j];
                sd[p][j] = __expf(fmaf(-50.0f * s, s, lw[p][mi4 + mj]));
            }
        }

        // 3) weighted x accumulation + denominator.
        #pragma unroll
        for (int c = 0; c < 3; c++) {
            const float2* px = (const float2*)&sx[c][ly + i][lx2];
            float2 x0 = px[0], x1 = px[1], x2 = px[2], x3 = px[3];
            float rx[8] = {x0.x,x0.y, x1.x,x1.y, x2.x,x2.y, x3.x,x3.y};
            #pragma unroll
            for (int p = 0; p < TPX; p++) {
                float a = acc[p][c];
                #pragma unroll
                for (int j = 0; j < 7; j++)
                    a = fmaf(rx[p + j], sd[p][j], a);
                acc[p][c] = a;
            }
        }
        #pragma unroll
        for (int p = 0; p < TPX; p++)
            #pragma unroll
            for (int j = 0; j < 7; j++) den[p] += sd[p][j];
    }

    float inv[TPX];
    #pragma unroll
    for (int p = 0; p < TPX; p++) inv[p] = 1.0f / den[p];

    #pragma unroll
    for (int c = 0; c < 3; c++) {
        float2 o;
        o.x = acc[0][c] * inv[0];
        o.y = acc[1][c] * inv[1];
        *(float2*)(out + (size_t)(b * 3 + c) * plane + (size_t)h * W_IMG + wb) = o;
    }
}

extern "C" void kernel_launch(void* const* d_in, const int* in_sizes, int n_in,
                              void* d_out, int out_size, void* d_ws, size_t ws_size,
                              hipStream_t stream) {
    const float* x  = (const float*)d_in[0];
    const float* g  = (const float*)d_in[1];
    const float* w0 = (const float*)d_in[2];
    float* out = (float*)d_out;

    dim3 block(BX, BY, 1);
    dim3 grid(W_IMG / TILE_W, H_IMG / TILE_H, 2);
    AdaptiveFilter_71416716198124_kernel<<<grid, block, 0, stream>>>(x, g, w0, out);
}

// Round 4
// 94.907 us; speedup vs baseline: 1.1290x; 1.0793x over previous
//
#include <hip/hip_runtime.h>

#define TILE_W 32
#define TILE_H 8
#define HALO 3
#define SW_ (TILE_W + 2*HALO)   // 38
#define SH_ (TILE_H + 2*HALO)   // 14
#define H_IMG 512
#define W_IMG 512
#define C_IMG 3

__device__ __forceinline__ int reflect_idx(int q, int n) {
    q = (q < 0) ? -q : q;
    q = (q >= n) ? (2 * n - 2 - q) : q;
    return q;
}

// Round-1 configuration: measured at the HBM roofline (~8 us kernel vs
// 8.3 us ideal for 52.4 MB of irreducible traffic). TPX=2/4 multi-pixel
// variants regressed via register pressure; keep this scalar form.
__global__ __launch_bounds__(256) void AdaptiveFilter_71416716198124_kernel(
    const float* __restrict__ x,
    const float* __restrict__ g,
    const float* __restrict__ w0,
    float* __restrict__ out)
{
    __shared__ float sg[C_IMG][SH_][SW_];
    __shared__ float sx[C_IMG][SH_][SW_];

    const int b  = blockIdx.z;
    const int h0 = blockIdx.y * TILE_H;
    const int w0c = blockIdx.x * TILE_W;
    const int tid = threadIdx.y * TILE_W + threadIdx.x;

    const int plane = H_IMG * W_IMG;
    const float* gb = g + (size_t)b * C_IMG * plane;
    const float* xb = x + (size_t)b * C_IMG * plane;

    // Stage tile + halo (reflect at image borders) into LDS.
    for (int idx = tid; idx < C_IMG * SH_ * SW_; idx += TILE_W * TILE_H) {
        int c = idx / (SH_ * SW_);
        int r = idx - c * (SH_ * SW_);
        int sh = r / SW_;
        int sw = r - sh * SW_;
        int gh = reflect_idx(h0 + sh - HALO, H_IMG);
        int gw = reflect_idx(w0c + sw - HALO, W_IMG);
        int off = c * plane + gh * W_IMG + gw;
        sg[c][sh][sw] = gb[off];
        sx[c][sh][sw] = xb[off];
    }
    __syncthreads();

    const int lx = threadIdx.x, ly = threadIdx.y;
    const int h = h0 + ly, w = w0c + lx;

    // 16 stored half-kernel logits, contiguous per pixel (64B -> 4x float4).
    const float4* wp = (const float4*)(w0 + ((size_t)((b * plane) + h * W_IMG + w) << 4));
    float4 a0 = wp[0], a1 = wp[1], a2 = wp[2], a3 = wp[3];
    float wv[16] = {a0.x, a0.y, a0.z, a0.w, a1.x, a1.y, a1.z, a1.w,
                    a2.x, a2.y, a2.z, a2.w, a3.x, a3.y, a3.z, a3.w};
    float mx = wv[0];
    #pragma unroll
    for (int i = 1; i < 16; i++) mx = fmaxf(mx, wv[i]);

    const float gc0 = sg[0][ly + HALO][lx + HALO];
    const float gc1 = sg[1][ly + HALO][lx + HALO];
    const float gc2 = sg[2][ly + HALO][lx + HALO];

    float n0 = 0.f, n1 = 0.f, n2 = 0.f, den = 0.f;
    // Softmax denominator cancels in num/den: wt = exp(l - max - 50*dist).
    #pragma unroll
    for (int i = 0; i < 7; i++) {
        const int mi = (i < 4) ? i : 6 - i;
        #pragma unroll
        for (int j = 0; j < 7; j++) {
            const int mj = (j < 4) ? j : 6 - j;
            float d0 = fabsf(sg[0][ly + i][lx + j] - gc0);
            float d1 = fabsf(sg[1][ly + i][lx + j] - gc1);
            float d2 = fabsf(sg[2][ly + i][lx + j] - gc2);
            float s = d0 + d1 + d2;
            float wt = __expf(wv[mi * 4 + mj] - mx - 50.0f * (s * s));
            n0 = fmaf(sx[0][ly + i][lx + j], wt, n0);
            n1 = fmaf(sx[1][ly + i][lx + j], wt, n1);
            n2 = fmaf(sx[2][ly + i][lx + j], wt, n2);
            den += wt;
        }
    }
    const float inv = 1.0f / den;
    size_t ob = (size_t)b * C_IMG * plane + (size_t)h * W_IMG + w;
    out[ob]             = n0 * inv;
    out[ob + plane]     = n1 * inv;
    out[ob + 2 * plane] = n2 * inv;
}

extern "C" void kernel_launch(void* const* d_in, const int* in_sizes, int n_in,
                              void* d_out, int out_size, void* d_ws, size_t ws_size,
                              hipStream_t stream) {
    const float* x  = (const float*)d_in[0];
    const float* g  = (const float*)d_in[1];
    const float* w0 = (const float*)d_in[2];
    float* out = (float*)d_out;

    dim3 block(TILE_W, TILE_H, 1);
    dim3 grid(W_IMG / TILE_W, H_IMG / TILE_H, 2);
    AdaptiveFilter_71416716198124_kernel<<<grid, block, 0, stream>>>(x, g, w0, out);
}